// Round 1
// baseline (202.946 us; speedup 1.0000x reference)
//
#include <hip/hip_runtime.h>
#include <stdint.h>

typedef float  f32x4  __attribute__((ext_vector_type(4)));
typedef float  f32x16 __attribute__((ext_vector_type(16)));
typedef short  s16x8  __attribute__((ext_vector_type(8)));
typedef unsigned short u16x4 __attribute__((ext_vector_type(4)));

#define LPAD 2052   // L + 4 padded positions per batch row

__device__ __forceinline__ float bf2f(unsigned short u){
  unsigned v = ((unsigned)u) << 16;
  return __builtin_bit_cast(float, v);
}
__device__ __forceinline__ unsigned short f2bf(float f){
  unsigned u = __builtin_bit_cast(unsigned, f);
  u += 0x7fffu + ((u >> 16) & 1u);
  return (unsigned short)(u >> 16);
}
__device__ __forceinline__ unsigned cvt_pk_bf16(float lo, float hi){
  unsigned r;
  asm volatile("v_cvt_pk_bf16_f32 %0, %1, %2" : "=v"(r) : "v"(lo), "v"(hi));
  return r;
}

// ---------------- K0: fp32 -> bf16 convert (vectorized) ----------------
__global__ void k_cvt(const float* __restrict__ src, unsigned short* __restrict__ dst, int n4){
  int i = blockIdx.x * 256 + threadIdx.x;
  if (i >= n4) return;
  f32x4 v = ((const f32x4*)src)[i];
  u16x4 o;
  o[0] = f2bf(v[0]); o[1] = f2bf(v[1]); o[2] = f2bf(v[2]); o[3] = f2bf(v[3]);
  ((u16x4*)dst)[i] = o;
}

// ---------------- K0b: write identity pad matrices ----------------
__global__ void k_eye(unsigned short* __restrict__ H){
  int t = blockIdx.x * 256 + threadIdx.x;       // B*4*1024 = 32768
  int b = t >> 12;
  int r = t & 4095;
  int which = r >> 10;                           // 0..3
  int ij = r & 1023;
  int p = (which < 2) ? which : (2048 + which);  // 0,1,2050,2051
  H[((size_t)(b * LPAD + p) << 10) + ij] = ((ij >> 5) == (ij & 31)) ? 0x3F80 : 0;
}

// ---------------- K1: h = X * W^T + bias  (bf16 MFMA GEMM, m97 structure) ----------------
__global__ __launch_bounds__(256) void k_gemm(const unsigned short* __restrict__ A,   // [16384][1024] bf16
                                              const unsigned short* __restrict__ Bw,  // [1024][1024] bf16 (N,K)
                                              const float* __restrict__ bias,
                                              unsigned short* __restrict__ H){        // [B*2052][1024] bf16
  __shared__ unsigned short sA[128 * 32];
  __shared__ unsigned short sB[128 * 32];
  const int tid = threadIdx.x;
  const int w = tid >> 6, l = tid & 63;
  const int bn = blockIdx.x, bm = blockIdx.y;    // bn fastest: 8 blocks share A tile
  const int M0 = bm * 128, N0 = bn * 128;
  const int wm = (w >> 1) * 64, wn = (w & 1) * 64;
  const int lm = l & 15, lk = l >> 4;
  f32x4 acc[4][4] = {};

  for (int kk = 0; kk < 1024; kk += 32){
    #pragma unroll
    for (int t = 0; t < 2; t++){
      int c = t * 256 + tid;
      const unsigned short* ga = A  + (size_t)(M0 + (c >> 2)) * 1024 + (kk + ((c & 3) << 3));
      __builtin_amdgcn_global_load_lds((const __attribute__((address_space(1))) void*)ga,
                                       (__attribute__((address_space(3))) void*)&sA[(t * 256 + w * 64) * 8],
                                       16, 0, 0);
      const unsigned short* gb = Bw + (size_t)(N0 + (c >> 2)) * 1024 + (kk + ((c & 3) << 3));
      __builtin_amdgcn_global_load_lds((const __attribute__((address_space(1))) void*)gb,
                                       (__attribute__((address_space(3))) void*)&sB[(t * 256 + w * 64) * 8],
                                       16, 0, 0);
    }
    __syncthreads();
    s16x8 aF[4], bF[4];
    #pragma unroll
    for (int m = 0; m < 4; m++) aF[m] = *(const s16x8*)&sA[(wm + m * 16 + lm) * 32 + lk * 8];
    #pragma unroll
    for (int n = 0; n < 4; n++) bF[n] = *(const s16x8*)&sB[(wn + n * 16 + lm) * 32 + lk * 8];
    #pragma unroll
    for (int m = 0; m < 4; m++){
      #pragma unroll
      for (int n = 0; n < 4; n++){
        acc[m][n] = __builtin_amdgcn_mfma_f32_16x16x32_bf16(aF[m], bF[n], acc[m][n], 0, 0, 0);
      }
    }
    __syncthreads();
  }

  float bv[4];
  #pragma unroll
  for (int n = 0; n < 4; n++) bv[n] = bias[N0 + wn + n * 16 + lm];
  #pragma unroll
  for (int m = 0; m < 4; m++){
    #pragma unroll
    for (int r = 0; r < 4; r++){
      int gm = M0 + wm + m * 16 + lk * 4 + r;
      int bb = gm >> 11, li = gm & 2047;
      unsigned short* orow = H + ((size_t)(bb * LPAD + 2 + li) << 10);
      #pragma unroll
      for (int n = 0; n < 4; n++){
        orow[N0 + wn + n * 16 + lm] = f2bf(acc[m][n][r] + bv[n]);
      }
    }
  }
}

// ---------------- K2: partial[p][f*5+k] = <h_pad[p], W_attn[f, e*5+k]> ----------------
__global__ __launch_bounds__(256) void k_partial(const unsigned short* __restrict__ H,
                                                 const float* __restrict__ Wattn,   // [5][5120] fp32
                                                 float* __restrict__ part){         // [16416][25]
  __shared__ unsigned short wl[25 * 1024];
  const int tid = threadIdx.x;
  for (int i = tid; i < 25600; i += 256){
    int fk = i >> 10, e = i & 1023;
    int f = fk / 5, k = fk - f * 5;
    wl[fk * 1024 + e] = f2bf(Wattn[f * 5120 + e * 5 + k]);
  }
  __syncthreads();
  const int w = tid >> 6, l = tid & 63;
  for (int i = 0; i < 4; i++){
    int p = blockIdx.x * 16 + w * 4 + i;
    const unsigned short* hp = H + ((size_t)p << 10);
    s16x8 h0 = *(const s16x8*)(hp + 16 * l);
    s16x8 h1 = *(const s16x8*)(hp + 16 * l + 8);
    float hh[16];
    #pragma unroll
    for (int j = 0; j < 8; j++){ hh[j] = bf2f((unsigned short)h0[j]); hh[8 + j] = bf2f((unsigned short)h1[j]); }
    float acc[25];
    #pragma unroll
    for (int fk = 0; fk < 25; fk++){
      s16x8 w0 = *(const s16x8*)&wl[fk * 1024 + 16 * l];
      s16x8 w1 = *(const s16x8*)&wl[fk * 1024 + 16 * l + 8];
      float a = 0.f;
      #pragma unroll
      for (int j = 0; j < 8; j++) a += hh[j] * bf2f((unsigned short)w0[j]);
      #pragma unroll
      for (int j = 0; j < 8; j++) a += hh[8 + j] * bf2f((unsigned short)w1[j]);
      acc[fk] = a;
    }
    #pragma unroll
    for (int fk = 0; fk < 25; fk++){
      float a = acc[fk];
      a += __shfl_xor(a, 32, 64);
      a += __shfl_xor(a, 16, 64);
      a += __shfl_xor(a, 8, 64);
      a += __shfl_xor(a, 4, 64);
      a += __shfl_xor(a, 2, 64);
      a += __shfl_xor(a, 1, 64);
      acc[fk] = a;
    }
    if (l == 0){
      float* o = part + (size_t)p * 25;
      #pragma unroll
      for (int fk = 0; fk < 25; fk++) o[fk] = acc[fk];
    }
  }
}

// ---------------- K3: scores -> leaky_relu -> softmax -> s = prod(alpha) ----------------
__global__ void k_alpha(const float* __restrict__ part, const float* __restrict__ battn,
                        float* __restrict__ sprod){
  int t = blockIdx.x * 256 + threadIdx.x;
  if (t >= 16384) return;
  int bb = t >> 11, li = t & 2047;
  int pbase = bb * LPAD + li;
  float sc[5];
  #pragma unroll
  for (int f = 0; f < 5; f++){
    float a = battn[f];
    #pragma unroll
    for (int k = 0; k < 5; k++) a += part[(size_t)(pbase + k) * 25 + f * 5 + k];
    sc[f] = (a > 0.f) ? a : 0.01f * a;
  }
  float m = sc[0];
  #pragma unroll
  for (int f = 1; f < 5; f++) m = fmaxf(m, sc[f]);
  float e0 = expf(sc[0] - m), e1 = expf(sc[1] - m), e2 = expf(sc[2] - m),
        e3 = expf(sc[3] - m), e4 = expf(sc[4] - m);
  float ssum = e0 + e1 + e2 + e3 + e4;
  float inv = 1.f / ssum;
  float inv2 = inv * inv;
  sprod[t] = (e0 * e1 * e2 * e3 * e4) * inv2 * inv2 * inv;
}

// ---------------- K4: per-position 32x32 matrix chain (MFMA), scaled by s ----------------
__global__ __launch_bounds__(256) void k_chain(const unsigned short* __restrict__ H,
                                               const float* __restrict__ sp,
                                               float* __restrict__ out){
  const int tid = threadIdx.x;
  const int w = tid >> 6, l = tid & 63;
  const int pos = blockIdx.x * 4 + w;
  const int bb = pos >> 11, li = pos & 2047;
  const unsigned short* hbase = H + ((size_t)(bb * LPAD + li) << 10);
  const int col = l & 31;
  const int kh = (l >> 5) << 3;   // 0 or 8

  // initial carried matrix M = h4, loaded directly as B-fragments (col-major access)
  const unsigned short* h4 = hbase + 4 * 1024;
  unsigned q0, q1, q2, q3, q4, q5, q6, q7;
  {
    #define LD2(kk) ((unsigned)h4[(kk) * 32 + col] | ((unsigned)h4[((kk) + 1) * 32 + col] << 16))
    q0 = LD2(kh + 0);  q1 = LD2(kh + 2);  q2 = LD2(kh + 4);  q3 = LD2(kh + 6);
    q4 = LD2(kh + 16); q5 = LD2(kh + 18); q6 = LD2(kh + 20); q7 = LD2(kh + 22);
    #undef LD2
  }
  union { unsigned u[4]; s16x8 v; } ub0, ub1;
  ub0.u[0] = q0; ub0.u[1] = q1; ub0.u[2] = q2; ub0.u[3] = q3;
  ub1.u[0] = q4; ub1.u[1] = q5; ub1.u[2] = q6; ub1.u[3] = q7;
  s16x8 Bf0 = ub0.v, Bf1 = ub1.v;

  f32x16 acc;
  #pragma unroll
  for (int st = 0; st < 4; st++){
    const int km = 3 - st;                       // M = h_km * M
    const unsigned short* hA = hbase + (km << 10);
    s16x8 A0 = *(const s16x8*)(hA + col * 32 + kh);        // k = kh..kh+7   (K half 0)
    s16x8 A1 = *(const s16x8*)(hA + col * 32 + kh + 16);   // k = 16+kh..    (K half 1)
    f32x16 z = {0,0,0,0,0,0,0,0,0,0,0,0,0,0,0,0};
    acc = __builtin_amdgcn_mfma_f32_32x32x16_bf16(A0, Bf0, z,   0, 0, 0);
    acc = __builtin_amdgcn_mfma_f32_32x32x16_bf16(A1, Bf1, acc, 0, 0, 0);
    if (st < 3){
      // C (col=lane&31, row=(t&3)+8*(t>>2)+4*(l>>5)) -> next B-frags (col=lane%32, k=8*(l/32)+j)
      unsigned d0 = cvt_pk_bf16(acc[0],  acc[1]);
      unsigned d1 = cvt_pk_bf16(acc[2],  acc[3]);
      unsigned d2 = cvt_pk_bf16(acc[4],  acc[5]);
      unsigned d3 = cvt_pk_bf16(acc[6],  acc[7]);
      unsigned d4 = cvt_pk_bf16(acc[8],  acc[9]);
      unsigned d5 = cvt_pk_bf16(acc[10], acc[11]);
      unsigned d6 = cvt_pk_bf16(acc[12], acc[13]);
      unsigned d7 = cvt_pk_bf16(acc[14], acc[15]);
      unsigned p0 = __shfl_xor(d0, 32, 64);
      unsigned p1 = __shfl_xor(d1, 32, 64);
      unsigned p2 = __shfl_xor(d2, 32, 64);
      unsigned p3 = __shfl_xor(d3, 32, 64);
      unsigned p4 = __shfl_xor(d4, 32, 64);
      unsigned p5 = __shfl_xor(d5, 32, 64);
      unsigned p6 = __shfl_xor(d6, 32, 64);
      unsigned p7 = __shfl_xor(d7, 32, 64);
      const bool lo = (l < 32);
      ub0.u[0] = lo ? d0 : p2;  ub0.u[1] = lo ? d1 : p3;
      ub0.u[2] = lo ? p0 : d2;  ub0.u[3] = lo ? p1 : d3;
      ub1.u[0] = lo ? d4 : p6;  ub1.u[1] = lo ? d5 : p7;
      ub1.u[2] = lo ? p4 : d6;  ub1.u[3] = lo ? p5 : d7;
      Bf0 = ub0.v; Bf1 = ub1.v;
    }
  }

  const float sv = sp[pos];
  float* ob = out + ((size_t)pos << 10);
  #pragma unroll
  for (int t = 0; t < 16; t++){
    int row = (t & 3) + 8 * (t >> 2) + ((l >> 5) << 2);
    ob[row * 32 + col] = sv * acc[t];
  }
}

// ---------------- launcher ----------------
extern "C" void kernel_launch(void* const* d_in, const int* in_sizes, int n_in,
                              void* d_out, int out_size, void* d_ws, size_t ws_size,
                              hipStream_t stream){
  const float* X  = (const float*)d_in[0];   // [8][2048][32][32]
  const float* Wd = (const float*)d_in[1];   // [1024][1024]
  const float* bd = (const float*)d_in[2];   // [1024]
  const float* Wa = (const float*)d_in[3];   // [5][5120]
  const float* ba = (const float*)d_in[4];   // [5]
  float* out = (float*)d_out;

  char* ws = (char*)d_ws;
  unsigned short* Hpad = (unsigned short*)ws;                               // 8*2052*1024*2 = 33,619,968 B
  unsigned short* Wbf  = (unsigned short*)(ws + 33619968);                  // 2,097,152 B
  float*          part = (float*)(ws + 33619968 + 2097152);                 // 16416*25*4 = 1,641,600 B
  float*          sprod= (float*)(ws + 33619968 + 2097152 + 1641600);       // 65,536 B
  unsigned short* Xbf  = (unsigned short*)d_out;  // 32 MiB scratch inside 64 MiB output; dead before k_chain writes

  k_cvt<<<16384, 256, 0, stream>>>(X, Xbf, 4194304);       // 16.78M elems / 4
  k_cvt<<<1024, 256, 0, stream>>>(Wd, Wbf, 262144);        // 1.05M elems / 4
  k_eye<<<128, 256, 0, stream>>>(Hpad);
  dim3 g1(8, 128);
  k_gemm<<<g1, 256, 0, stream>>>(Xbf, Wbf, bd, Hpad);
  k_partial<<<1026, 256, 0, stream>>>(Hpad, Wa, part);
  k_alpha<<<64, 256, 0, stream>>>(part, ba, sprod);
  k_chain<<<4096, 256, 0, stream>>>(Hpad, sprod, out);
}